// Round 4
// baseline (311.694 us; speedup 1.0000x reference)
//
#include <hip/hip_runtime.h>
#include <hip/hip_bf16.h>
#include <cstdint>
#include <cstddef>

// LearnableUpsampler: quant -> convT(K=4,s=2) -> quant -> conv7+silu -> quant -> conv7 + res -> LN
// Round 4: barrier-free K-loop. A staged to LDS once per block (one __syncthreads total);
// B (ternary weights, L2-resident) loaded straight to VGPRs as coalesced dwordx4 — no
// per-chunk staging, no vmcnt(0) drains. Wave tile 64x64 (2x2 accs), block 64M x 128N.

#define B_ 2
#define T_ 2048
#define L_ 4096
#define C_ 512

static constexpr int NUP = 512 * 512 * 4;
static constexpr int NR  = 512 * 512 * 7;

using v4i  = __attribute__((ext_vector_type(4))) int;
using v16i = __attribute__((ext_vector_type(16))) int;

__device__ __forceinline__ void gl16(const void* g, void* l) {
  __builtin_amdgcn_global_load_lds((const __attribute__((address_space(1))) unsigned int*)g,
                                   (__attribute__((address_space(3))) unsigned int*)l,
                                   16, 0, 0);
}

// ---------------- reductions ----------------

__device__ inline float block_reduce_sum_256(float v) {
  #pragma unroll
  for (int off = 32; off > 0; off >>= 1) v += __shfl_down(v, off, 64);
  __shared__ float s[4];
  __syncthreads();
  if ((threadIdx.x & 63) == 0) s[threadIdx.x >> 6] = v;
  __syncthreads();
  return (s[0] + s[1]) + (s[2] + s[3]);
}

__global__ void abssum_kernel(const float* __restrict__ w, int n, float* __restrict__ out) {
  int idx = blockIdx.x * 256 + threadIdx.x;
  float s = 0.f;
  for (int i = idx; i < n; i += gridDim.x * 256) s += fabsf(w[i]);
  s = block_reduce_sum_256(s);
  if (threadIdx.x == 0) atomicAdd(out, s);
}

// ---------------- ternarize + repack to [tap][kq32][co512][16] ----------------
// conv7 weights: input w (co, ci, 7); kq32 = ci>>4
__global__ void tern_7_kernel(const float* __restrict__ w, int8_t* __restrict__ o,
                              const float* __restrict__ wsum, int widx) {
  int idx = blockIdx.x * 256 + threadIdx.x;
  if (idx >= NR) return;
  float mean = wsum[widx] * (1.0f / (float)NR);
  float scale = 1.0f / fmaxf(mean, 1e-5f);
  float t = rintf(w[idx] * scale);
  t = fminf(fmaxf(t, -1.f), 1.f);
  int co = idx / 3584;
  int rem = idx - co * 3584;
  int ci = rem / 7;
  int k = rem - ci * 7;
  o[(((size_t)k * 32 + (ci >> 4)) * 512 + co) * 16 + (ci & 15)] = (int8_t)t;
}

// convT weights: input w (ci, co, 4); ptap order: parity0 {k=3,k=1}, parity1 {k=2,k=0}
__global__ void tern_up_kernel(const float* __restrict__ w, int8_t* __restrict__ o,
                               const float* __restrict__ wsum) {
  int idx = blockIdx.x * 256 + threadIdx.x;
  if (idx >= NUP) return;
  float mean = wsum[0] * (1.0f / (float)NUP);
  float scale = 1.0f / fmaxf(mean, 1e-5f);
  float t = rintf(w[idx] * scale);
  t = fminf(fmaxf(t, -1.f), 1.f);
  int ci = idx >> 11;
  int co = (idx >> 2) & 511;
  int k = idx & 3;
  int ptap = (k == 3) ? 0 : (k == 1) ? 1 : (k == 2) ? 2 : 3;
  o[(((size_t)ptap * 32 + (ci >> 4)) * 512 + co) * 16 + (ci & 15)] = (int8_t)t;
}

// ---------------- per-token activation quant; packed q layout [b][kq32][LinH][16] ----------------
__global__ void act_quant_kernel(const float* __restrict__ x, int8_t* __restrict__ qd,
                                 float* __restrict__ inv, int Lb, int lbsh, int LinH) {
  int tok = blockIdx.x;
  int b = tok >> lbsh;
  int t = tok & (Lb - 1);
  const float* row = x + (size_t)tok * C_;
  int tid = threadIdx.x;
  float v0 = row[tid];
  float v1 = row[tid + 256];
  float m = fmaxf(fabsf(v0), fabsf(v1));
  #pragma unroll
  for (int off = 32; off > 0; off >>= 1) m = fmaxf(m, __shfl_down(m, off, 64));
  __shared__ float s[4];
  if ((tid & 63) == 0) s[tid >> 6] = m;
  __syncthreads();
  m = fmaxf(fmaxf(s[0], s[1]), fmaxf(s[2], s[3]));
  float scale = 127.0f / fmaxf(m, 1e-5f);
  float q0 = fminf(fmaxf(rintf(v0 * scale), -128.f), 127.f);
  float q1 = fminf(fmaxf(rintf(v1 * scale), -128.f), 127.f);
  int ci0 = tid, ci1 = tid + 256;
  qd[((size_t)(b * 32 + (ci0 >> 4)) * LinH + 8 + t) * 16 + (ci0 & 15)] = (int8_t)q0;
  qd[((size_t)(b * 32 + (ci1 >> 4)) * LinH + 8 + t) * 16 + (ci1 & 15)] = (int8_t)q1;
  if (tid == 0) inv[(size_t)b * LinH + 8 + t] = 1.0f / scale;
}

// ---------------- MFMA conv: barrier-free per-tap int8 GEMM ----------------
// Block 128 thr (2 waves), tile 64(M) x 128(N); wave w covers cols [64w, 64w+64).
// sA[kq32][row80][16] staged once (rows t0-8..t0+71); ONE barrier; then pure dataflow:
// per k-step: 2 ds_read_b128 (A), 2 global_load_dwordx4 (B, L2-resident), 4 MFMA.
template<int NTAPS, bool CONVT>
__global__ __launch_bounds__(128, 1)
void conv_mfma(const int8_t* __restrict__ qin, const float* __restrict__ invp, int LinH,
               const int8_t* __restrict__ wq, const float* __restrict__ wsum, int widx,
               float wninv, const float* __restrict__ bias, const float* __restrict__ res,
               float* __restrict__ outp, int Lout, int do_silu) {
  __shared__ __align__(16) int8_t sA[32 * 80 * 16];  // 40960 B
  __shared__ float sInv[80];

  const int tid = threadIdx.x;
  const int w = tid >> 6, lane = tid & 63, q = lane >> 5, l31 = lane & 31;
  const int n0 = (blockIdx.x & 3) * 128;
  const int t0 = (blockIdx.x >> 2) * 64;
  const int b = blockIdx.y;
  int s0 = -3;
  const int8_t* wq_p = wq;
  float* out_b = outp + (size_t)b * Lout * 512;
  int rstride = 512;
  if (CONVT) {
    int parity = blockIdx.z;
    s0 = parity - 1;
    wq_p += (size_t)parity * 2 * 32 * 512 * 16;
    out_b += parity * 512;
    rstride = 1024;
  }
  const int8_t* qin_b = qin + (size_t)b * 32 * LinH * 16;
  const float* inv_b = invp + (size_t)b * LinH + 8;

  // stage A once: 2560 units of 16B, [kq32][row80][16]; global row t0-8+row -> buf row
  #pragma unroll
  for (int i = 0; i < 20; ++i) {
    int u = i * 128 + w * 64 + lane;
    int kq = u / 80;
    int row = u - kq * 80;
    gl16(qin_b + ((size_t)kq * LinH + (size_t)(t0 + row)) * 16,
         sA + (size_t)(i * 128 + w * 64) * 16);
  }
  if (tid < 80) sInv[tid] = inv_b[t0 - 8 + tid];
  __syncthreads();  // the ONLY barrier

  float fs[4][16];
  #pragma unroll
  for (int i = 0; i < 4; ++i)
    #pragma unroll
    for (int r = 0; r < 16; ++r) fs[i][r] = 0.f;

  const int nw = n0 + w * 64;
  const int abase = 8 + l31;

  for (int tap = 0; tap < NTAPS; ++tap) {
    const int shift = s0 + tap;
    v16i a00{}, a01{}, a10{}, a11{};
    #pragma unroll
    for (int r = 0; r < 16; ++r) { a00[r] = 0; a01[r] = 0; a10[r] = 0; a11[r] = 0; }
    const int8_t* wt = wq_p + (size_t)(tap * 32) * 512 * 16;
    #pragma unroll
    for (int ks = 0; ks < 16; ++ks) {
      int kq32 = ks * 2 + q;
      const int8_t* ap = sA + ((size_t)kq32 * 80 + abase + shift) * 16;
      v4i af0 = *(const v4i*)ap;
      v4i af1 = *(const v4i*)(ap + 32 * 16);
      const int8_t* bp = wt + ((size_t)kq32 * 512 + nw + l31) * 16;
      v4i bf0 = *(const v4i*)bp;
      v4i bf1 = *(const v4i*)(bp + 32 * 16);
      a00 = __builtin_amdgcn_mfma_i32_32x32x32_i8(af0, bf0, a00, 0, 0, 0);
      a01 = __builtin_amdgcn_mfma_i32_32x32x32_i8(af0, bf1, a01, 0, 0, 0);
      a10 = __builtin_amdgcn_mfma_i32_32x32x32_i8(af1, bf0, a10, 0, 0, 0);
      a11 = __builtin_amdgcn_mfma_i32_32x32x32_i8(af1, bf1, a11, 0, 0, 0);
    }
    // fold i32 -> fp32 with per-input-row scale
    #pragma unroll
    for (int r = 0; r < 16; ++r) {
      int ro = (r & 3) + 8 * (r >> 2) + 4 * q;
      float sc0 = sInv[8 + shift + ro];
      float sc1 = sInv[8 + shift + 32 + ro];
      fs[0][r] = fmaf((float)a00[r], sc0, fs[0][r]);
      fs[1][r] = fmaf((float)a01[r], sc0, fs[1][r]);
      fs[2][r] = fmaf((float)a10[r], sc1, fs[2][r]);
      fs[3][r] = fmaf((float)a11[r], sc1, fs[3][r]);
    }
  }

  float wdq = fmaxf(wsum[widx] * wninv, 1e-5f);
  #pragma unroll
  for (int mt = 0; mt < 2; ++mt)
    #pragma unroll
    for (int nt = 0; nt < 2; ++nt) {
      int col = nw + nt * 32 + l31;
      float bv = bias[col];
      #pragma unroll
      for (int r = 0; r < 16; ++r) {
        int row = t0 + mt * 32 + (r & 3) + 8 * (r >> 2) + 4 * q;
        float y = fs[mt * 2 + nt][r] * wdq + bv;
        if (do_silu) y = y / (1.0f + expf(-y));
        if (res) y += res[((size_t)b * Lout + row) * 512 + col];
        out_b[(size_t)row * rstride + col] = y;
      }
    }
}

// ---------------- LayerNorm over channels ----------------
__global__ void ln_kernel(const float* __restrict__ x, const float* __restrict__ g,
                          const float* __restrict__ be, float* __restrict__ out) {
  int tok = blockIdx.x;
  const float* row = x + (size_t)tok * C_;
  int tid = threadIdx.x;
  float v0 = row[tid];
  float v1 = row[tid + 256];
  float total = block_reduce_sum_256(v0 + v1);
  float mu = total * (1.0f / (float)C_);
  float d0 = v0 - mu, d1 = v1 - mu;
  float vs = block_reduce_sum_256(d0 * d0 + d1 * d1);
  float var = vs * (1.0f / (float)C_);
  float r = 1.0f / sqrtf(var + 1e-5f);
  size_t base = (size_t)tok * C_;
  out[base + tid] = d0 * r * g[tid] + be[tid];
  out[base + tid + 256] = d1 * r * g[tid + 256] + be[tid + 256];
}

// ---------------- launch ----------------

extern "C" void kernel_launch(void* const* d_in, const int* in_sizes, int n_in,
                              void* d_out, int out_size, void* d_ws, size_t ws_size,
                              hipStream_t stream) {
  const float* x    = (const float*)d_in[0];
  const float* w_up = (const float*)d_in[1];
  const float* b_up = (const float*)d_in[2];
  const float* w_r1 = (const float*)d_in[3];
  const float* b_r1 = (const float*)d_in[4];
  const float* w_r2 = (const float*)d_in[5];
  const float* b_r2 = (const float*)d_in[6];
  const float* ln_w = (const float*)d_in[7];
  const float* ln_b = (const float*)d_in[8];
  float* out = (float*)d_out;

  const int LXH = T_ + 16;   // 2064 rows per batch (halo 8 each side)
  const int LHH = L_ + 16;   // 4112

  char* ws = (char*)d_ws;
  size_t off = 0;
  auto alloc = [&](size_t sz) { size_t p = off; off += (sz + 255) & ~(size_t)255; return p; };
  float*  wsum = (float*) (ws + alloc(256));
  int8_t* qx   = (int8_t*)(ws + alloc((size_t)B_ * 32 * LXH * 16));   // 2.1 MB
  float*  invx = (float*) (ws + alloc((size_t)B_ * LXH * 4));
  int8_t* wqup = (int8_t*)(ws + alloc((size_t)4 * 32 * 512 * 16));    // 1 MB
  int8_t* wq1  = (int8_t*)(ws + alloc((size_t)7 * 32 * 512 * 16));    // 1.8 MB
  int8_t* wq2  = (int8_t*)(ws + alloc((size_t)7 * 32 * 512 * 16));    // 1.8 MB
  float*  h    = (float*) (ws + alloc((size_t)B_ * L_ * C_ * 4));     // 16.8 MB
  int8_t* qh   = (int8_t*)(ws + alloc((size_t)B_ * 32 * LHH * 16));   // 4.2 MB
  float*  invh = (float*) (ws + alloc((size_t)B_ * LHH * 4));
  float*  r    = (float*) (ws + alloc((size_t)B_ * L_ * C_ * 4));     // 16.8 MB

  hipMemsetAsync(wsum, 0, 256, stream);
  hipMemsetAsync(qx, 0, (size_t)B_ * 32 * LXH * 16, stream);  // zero halos
  hipMemsetAsync(qh, 0, (size_t)B_ * 32 * LHH * 16, stream);
  hipMemsetAsync(invx, 0, (size_t)B_ * LXH * 4, stream);
  hipMemsetAsync(invh, 0, (size_t)B_ * LHH * 4, stream);

  abssum_kernel<<<256, 256, 0, stream>>>(w_up, NUP, wsum + 0);
  abssum_kernel<<<256, 256, 0, stream>>>(w_r1, NR, wsum + 1);
  abssum_kernel<<<256, 256, 0, stream>>>(w_r2, NR, wsum + 2);

  tern_up_kernel<<<NUP / 256, 256, 0, stream>>>(w_up, wqup, wsum);
  tern_7_kernel<<<NR / 256, 256, 0, stream>>>(w_r1, wq1, wsum, 1);
  tern_7_kernel<<<NR / 256, 256, 0, stream>>>(w_r2, wq2, wsum, 2);

  act_quant_kernel<<<B_ * T_, 256, 0, stream>>>(x, qx, invx, T_, 11, LXH);

  // convT: grid (4 ntiles * 32 mtiles, B, parity); block tile 64M x 128N
  conv_mfma<2, true><<<dim3(4 * 32, B_, 2), 128, 0, stream>>>(
      qx, invx, LXH, wqup, wsum, 0, 1.0f / (float)NUP, b_up, nullptr, h, L_, 0);

  act_quant_kernel<<<B_ * L_, 256, 0, stream>>>(h, qh, invh, L_, 12, LHH);

  conv_mfma<7, false><<<dim3(4 * 64, B_, 1), 128, 0, stream>>>(
      qh, invh, LHH, wq1, wsum, 1, 1.0f / (float)NR, b_r1, nullptr, r, L_, 1);

  act_quant_kernel<<<B_ * L_, 256, 0, stream>>>(r, qh, invh, L_, 12, LHH);

  conv_mfma<7, false><<<dim3(4 * 64, B_, 1), 128, 0, stream>>>(
      qh, invh, LHH, wq2, wsum, 2, 1.0f / (float)NR, b_r2, h, r, L_, 0);

  ln_kernel<<<B_ * L_, 256, 0, stream>>>(r, ln_w, ln_b, out);
}

// Round 5
// 249.006 us; speedup vs baseline: 1.2518x; 1.2518x over previous
//
#include <hip/hip_runtime.h>
#include <hip/hip_bf16.h>
#include <cstdint>
#include <cstddef>

// LearnableUpsampler: quant -> convT(K=4,s=2) -> quant -> conv7+silu -> quant -> conv7 + res -> LN
// Round 5: TLP fix. M-tile 32, N-tile 128, block = 2 waves (wave tile 32x64, 2 accs).
// Grid 1024 blocks/conv = 4 blocks/CU = 8 waves/CU (2/SIMD). Barrier-free K-loop kept:
// A staged once to LDS (20.6 KB), B straight from L2 to VGPRs, explicit depth-1 prefetch.

#define B_ 2
#define T_ 2048
#define L_ 4096
#define C_ 512

static constexpr int NUP = 512 * 512 * 4;
static constexpr int NR  = 512 * 512 * 7;

using v4i  = __attribute__((ext_vector_type(4))) int;
using v16i = __attribute__((ext_vector_type(16))) int;

__device__ __forceinline__ void gl16(const void* g, void* l) {
  __builtin_amdgcn_global_load_lds((const __attribute__((address_space(1))) unsigned int*)g,
                                   (__attribute__((address_space(3))) unsigned int*)l,
                                   16, 0, 0);
}

// ---------------- reductions ----------------

__device__ inline float block_reduce_sum_256(float v) {
  #pragma unroll
  for (int off = 32; off > 0; off >>= 1) v += __shfl_down(v, off, 64);
  __shared__ float s[4];
  __syncthreads();
  if ((threadIdx.x & 63) == 0) s[threadIdx.x >> 6] = v;
  __syncthreads();
  return (s[0] + s[1]) + (s[2] + s[3]);
}

__global__ void abssum_kernel(const float* __restrict__ w, int n, float* __restrict__ out) {
  int idx = blockIdx.x * 256 + threadIdx.x;
  float s = 0.f;
  for (int i = idx; i < n; i += gridDim.x * 256) s += fabsf(w[i]);
  s = block_reduce_sum_256(s);
  if (threadIdx.x == 0) atomicAdd(out, s);
}

// ---------------- ternarize + repack to [tap][kq32][co512][16] ----------------
__global__ void tern_7_kernel(const float* __restrict__ w, int8_t* __restrict__ o,
                              const float* __restrict__ wsum, int widx) {
  int idx = blockIdx.x * 256 + threadIdx.x;
  if (idx >= NR) return;
  float mean = wsum[widx] * (1.0f / (float)NR);
  float scale = 1.0f / fmaxf(mean, 1e-5f);
  float t = rintf(w[idx] * scale);
  t = fminf(fmaxf(t, -1.f), 1.f);
  int co = idx / 3584;
  int rem = idx - co * 3584;
  int ci = rem / 7;
  int k = rem - ci * 7;
  o[(((size_t)k * 32 + (ci >> 4)) * 512 + co) * 16 + (ci & 15)] = (int8_t)t;
}

// convT weights: input w (ci, co, 4); ptap order: parity0 {k=3,k=1}, parity1 {k=2,k=0}
__global__ void tern_up_kernel(const float* __restrict__ w, int8_t* __restrict__ o,
                               const float* __restrict__ wsum) {
  int idx = blockIdx.x * 256 + threadIdx.x;
  if (idx >= NUP) return;
  float mean = wsum[0] * (1.0f / (float)NUP);
  float scale = 1.0f / fmaxf(mean, 1e-5f);
  float t = rintf(w[idx] * scale);
  t = fminf(fmaxf(t, -1.f), 1.f);
  int ci = idx >> 11;
  int co = (idx >> 2) & 511;
  int k = idx & 3;
  int ptap = (k == 3) ? 0 : (k == 1) ? 1 : (k == 2) ? 2 : 3;
  o[(((size_t)ptap * 32 + (ci >> 4)) * 512 + co) * 16 + (ci & 15)] = (int8_t)t;
}

// ---------------- per-token activation quant; packed q layout [b][kq32][LinH][16] ----------------
__global__ void act_quant_kernel(const float* __restrict__ x, int8_t* __restrict__ qd,
                                 float* __restrict__ inv, int Lb, int lbsh, int LinH) {
  int tok = blockIdx.x;
  int b = tok >> lbsh;
  int t = tok & (Lb - 1);
  const float* row = x + (size_t)tok * C_;
  int tid = threadIdx.x;
  float v0 = row[tid];
  float v1 = row[tid + 256];
  float m = fmaxf(fabsf(v0), fabsf(v1));
  #pragma unroll
  for (int off = 32; off > 0; off >>= 1) m = fmaxf(m, __shfl_down(m, off, 64));
  __shared__ float s[4];
  if ((tid & 63) == 0) s[tid >> 6] = m;
  __syncthreads();
  m = fmaxf(fmaxf(s[0], s[1]), fmaxf(s[2], s[3]));
  float scale = 127.0f / fmaxf(m, 1e-5f);
  float q0 = fminf(fmaxf(rintf(v0 * scale), -128.f), 127.f);
  float q1 = fminf(fmaxf(rintf(v1 * scale), -128.f), 127.f);
  int ci0 = tid, ci1 = tid + 256;
  qd[((size_t)(b * 32 + (ci0 >> 4)) * LinH + 8 + t) * 16 + (ci0 & 15)] = (int8_t)q0;
  qd[((size_t)(b * 32 + (ci1 >> 4)) * LinH + 8 + t) * 16 + (ci1 & 15)] = (int8_t)q1;
  if (tid == 0) inv[(size_t)b * LinH + 8 + t] = 1.0f / scale;
}

// ---------------- MFMA conv: barrier-free per-tap int8 GEMM ----------------
// Block 128 thr (2 waves), tile 32(M) x 128(N); wave w covers cols [64w, 64w+64).
// sA[kq32][row40][16] staged once (rows t0-4..t0+35); ONE barrier; then pure dataflow:
// per k-step per wave: 1 ds_read_b128 (A), 2 global_load_dwordx4 (B, L2), 2 MFMA.
template<int NTAPS, bool CONVT>
__global__ __launch_bounds__(128, 2)
void conv_mfma(const int8_t* __restrict__ qin, const float* __restrict__ invp, int LinH,
               const int8_t* __restrict__ wq, const float* __restrict__ wsum, int widx,
               float wninv, const float* __restrict__ bias, const float* __restrict__ res,
               float* __restrict__ outp, int Lout, int do_silu) {
  __shared__ __align__(16) int8_t sA[32 * 40 * 16];  // 20480 B
  __shared__ float sInv[40];

  const int tid = threadIdx.x;
  const int w = tid >> 6, lane = tid & 63, q = lane >> 5, l31 = lane & 31;
  const int n0 = (blockIdx.x & 3) * 128;
  const int t0 = (blockIdx.x >> 2) * 32;
  const int b = blockIdx.y;
  int s0 = -3;
  const int8_t* wq_p = wq;
  float* out_b = outp + (size_t)b * Lout * 512;
  int rstride = 512;
  if (CONVT) {
    int parity = blockIdx.z;
    s0 = parity - 1;
    wq_p += (size_t)parity * 2 * 32 * 512 * 16;
    out_b += parity * 512;
    rstride = 1024;
  }
  const int8_t* qin_b = qin + (size_t)b * 32 * LinH * 16;
  const float* inv_b = invp + (size_t)b * LinH + 8;

  // stage A once: 1280 units of 16B, [kq32][row40][16]; buf row r <-> token t0-4+r
  #pragma unroll
  for (int i = 0; i < 10; ++i) {
    int u = i * 128 + tid;
    int kq = u / 40;
    int row = u - kq * 40;
    gl16(qin_b + ((size_t)kq * LinH + (size_t)(t0 + 4 + row)) * 16,
         sA + (size_t)(i * 128 + w * 64) * 16);
  }
  if (tid < 40) sInv[tid] = inv_b[t0 - 4 + tid];
  __syncthreads();  // the ONLY barrier

  float fs0[16], fs1[16];
  #pragma unroll
  for (int r = 0; r < 16; ++r) { fs0[r] = 0.f; fs1[r] = 0.f; }

  const int nw = n0 + w * 64;

  for (int tap = 0; tap < NTAPS; ++tap) {
    const int shift = s0 + tap;
    const int arow = 4 + shift + l31;
    const int8_t* wt = wq_p + (size_t)(tap * 32) * 512 * 16;
    v16i acc0{}, acc1{};
    #pragma unroll
    for (int r = 0; r < 16; ++r) { acc0[r] = 0; acc1[r] = 0; }
    // prologue loads (kq32 = q)
    v4i af = *(const v4i*)(sA + ((size_t)q * 40 + arow) * 16);
    const int8_t* bp0 = wt + ((size_t)q * 512 + nw + l31) * 16;
    v4i bf0 = *(const v4i*)bp0;
    v4i bf1 = *(const v4i*)(bp0 + 512);
    #pragma unroll
    for (int ks = 0; ks < 16; ++ks) {
      v4i afc = af, b0c = bf0, b1c = bf1;
      if (ks < 15) {
        int kq32 = (ks + 1) * 2 + q;
        af = *(const v4i*)(sA + ((size_t)kq32 * 40 + arow) * 16);
        const int8_t* bp = wt + ((size_t)kq32 * 512 + nw + l31) * 16;
        bf0 = *(const v4i*)bp;
        bf1 = *(const v4i*)(bp + 512);
      }
      acc0 = __builtin_amdgcn_mfma_i32_32x32x32_i8(afc, b0c, acc0, 0, 0, 0);
      acc1 = __builtin_amdgcn_mfma_i32_32x32x32_i8(afc, b1c, acc1, 0, 0, 0);
    }
    // fold i32 -> fp32 with per-input-row scale
    #pragma unroll
    for (int r = 0; r < 16; ++r) {
      int ro = (r & 3) + 8 * (r >> 2) + 4 * q;
      float sc = sInv[4 + shift + ro];
      fs0[r] = fmaf((float)acc0[r], sc, fs0[r]);
      fs1[r] = fmaf((float)acc1[r], sc, fs1[r]);
    }
  }

  float wdq = fmaxf(wsum[widx] * wninv, 1e-5f);
  #pragma unroll
  for (int nt = 0; nt < 2; ++nt) {
    int col = nw + nt * 32 + l31;
    float bv = bias[col];
    #pragma unroll
    for (int r = 0; r < 16; ++r) {
      int row = t0 + (r & 3) + 8 * (r >> 2) + 4 * q;
      float y = (nt == 0 ? fs0[r] : fs1[r]) * wdq + bv;
      if (do_silu) y = y / (1.0f + expf(-y));
      if (res) y += res[((size_t)b * Lout + row) * 512 + col];
      out_b[(size_t)row * rstride + col] = y;
    }
  }
}

// ---------------- LayerNorm over channels ----------------
__global__ void ln_kernel(const float* __restrict__ x, const float* __restrict__ g,
                          const float* __restrict__ be, float* __restrict__ out) {
  int tok = blockIdx.x;
  const float* row = x + (size_t)tok * C_;
  int tid = threadIdx.x;
  float v0 = row[tid];
  float v1 = row[tid + 256];
  float total = block_reduce_sum_256(v0 + v1);
  float mu = total * (1.0f / (float)C_);
  float d0 = v0 - mu, d1 = v1 - mu;
  float vs = block_reduce_sum_256(d0 * d0 + d1 * d1);
  float var = vs * (1.0f / (float)C_);
  float r = 1.0f / sqrtf(var + 1e-5f);
  size_t base = (size_t)tok * C_;
  out[base + tid] = d0 * r * g[tid] + be[tid];
  out[base + tid + 256] = d1 * r * g[tid + 256] + be[tid + 256];
}

// ---------------- launch ----------------

extern "C" void kernel_launch(void* const* d_in, const int* in_sizes, int n_in,
                              void* d_out, int out_size, void* d_ws, size_t ws_size,
                              hipStream_t stream) {
  const float* x    = (const float*)d_in[0];
  const float* w_up = (const float*)d_in[1];
  const float* b_up = (const float*)d_in[2];
  const float* w_r1 = (const float*)d_in[3];
  const float* b_r1 = (const float*)d_in[4];
  const float* w_r2 = (const float*)d_in[5];
  const float* b_r2 = (const float*)d_in[6];
  const float* ln_w = (const float*)d_in[7];
  const float* ln_b = (const float*)d_in[8];
  float* out = (float*)d_out;

  const int LXH = T_ + 16;   // 2064 rows per batch (halo 8 each side)
  const int LHH = L_ + 16;   // 4112

  char* ws = (char*)d_ws;
  size_t off = 0;
  auto alloc = [&](size_t sz) { size_t p = off; off += (sz + 255) & ~(size_t)255; return p; };
  float*  wsum = (float*) (ws + alloc(256));
  int8_t* qx   = (int8_t*)(ws + alloc((size_t)B_ * 32 * LXH * 16));   // 2.1 MB
  float*  invx = (float*) (ws + alloc((size_t)B_ * LXH * 4));
  int8_t* wqup = (int8_t*)(ws + alloc((size_t)4 * 32 * 512 * 16));    // 1 MB
  int8_t* wq1  = (int8_t*)(ws + alloc((size_t)7 * 32 * 512 * 16));    // 1.8 MB
  int8_t* wq2  = (int8_t*)(ws + alloc((size_t)7 * 32 * 512 * 16));    // 1.8 MB
  float*  h    = (float*) (ws + alloc((size_t)B_ * L_ * C_ * 4));     // 16.8 MB
  int8_t* qh   = (int8_t*)(ws + alloc((size_t)B_ * 32 * LHH * 16));   // 4.2 MB
  float*  invh = (float*) (ws + alloc((size_t)B_ * LHH * 4));
  float*  r    = (float*) (ws + alloc((size_t)B_ * L_ * C_ * 4));     // 16.8 MB

  hipMemsetAsync(wsum, 0, 256, stream);
  hipMemsetAsync(qx, 0, (size_t)B_ * 32 * LXH * 16, stream);  // zero halos
  hipMemsetAsync(qh, 0, (size_t)B_ * 32 * LHH * 16, stream);
  hipMemsetAsync(invx, 0, (size_t)B_ * LXH * 4, stream);
  hipMemsetAsync(invh, 0, (size_t)B_ * LHH * 4, stream);

  abssum_kernel<<<256, 256, 0, stream>>>(w_up, NUP, wsum + 0);
  abssum_kernel<<<256, 256, 0, stream>>>(w_r1, NR, wsum + 1);
  abssum_kernel<<<256, 256, 0, stream>>>(w_r2, NR, wsum + 2);

  tern_up_kernel<<<NUP / 256, 256, 0, stream>>>(w_up, wqup, wsum);
  tern_7_kernel<<<NR / 256, 256, 0, stream>>>(w_r1, wq1, wsum, 1);
  tern_7_kernel<<<NR / 256, 256, 0, stream>>>(w_r2, wq2, wsum, 2);

  act_quant_kernel<<<B_ * T_, 256, 0, stream>>>(x, qx, invx, T_, 11, LXH);

  // convT: grid (4 ntiles * 64 mtiles, B, parity); block tile 32M x 128N
  conv_mfma<2, true><<<dim3(4 * 64, B_, 2), 128, 0, stream>>>(
      qx, invx, LXH, wqup, wsum, 0, 1.0f / (float)NUP, b_up, nullptr, h, L_, 0);

  act_quant_kernel<<<B_ * L_, 256, 0, stream>>>(h, qh, invh, L_, 12, LHH);

  conv_mfma<7, false><<<dim3(4 * 128, B_, 1), 128, 0, stream>>>(
      qh, invh, LHH, wq1, wsum, 1, 1.0f / (float)NR, b_r1, nullptr, r, L_, 1);

  act_quant_kernel<<<B_ * L_, 256, 0, stream>>>(r, qh, invh, L_, 12, LHH);

  conv_mfma<7, false><<<dim3(4 * 128, B_, 1), 128, 0, stream>>>(
      qh, invh, LHH, wq2, wsum, 2, 1.0f / (float)NR, b_r2, h, r, L_, 0);

  ln_kernel<<<B_ * L_, 256, 0, stream>>>(r, ln_w, ln_b, out);
}

// Round 6
// 236.851 us; speedup vs baseline: 1.3160x; 1.0513x over previous
//
#include <hip/hip_runtime.h>
#include <hip/hip_bf16.h>
#include <cstdint>
#include <cstddef>

// LearnableUpsampler: quant -> convT(K=4,s=2) -> quant -> conv7+silu -> quant -> conv7 + res -> LN
// Round 6: depth-4 rolling prefetch with cross-tap pipelining (fold overlaps in-flight
// loads); aux kernels merged (10 dispatches total). Block 32M x 128N, 2 waves, wave
// tile 32x64; A in LDS staged once (one barrier), B straight from L2.

#define B_ 2
#define T_ 2048
#define L_ 4096
#define C_ 512

static constexpr int NUP = 512 * 512 * 4;
static constexpr int NR  = 512 * 512 * 7;

using v4i  = __attribute__((ext_vector_type(4))) int;
using v16i = __attribute__((ext_vector_type(16))) int;

__device__ __forceinline__ void gl16(const void* g, void* l) {
  __builtin_amdgcn_global_load_lds((const __attribute__((address_space(1))) unsigned int*)g,
                                   (__attribute__((address_space(3))) unsigned int*)l,
                                   16, 0, 0);
}

// ---------------- reductions ----------------

__device__ inline float block_reduce_sum_256(float v) {
  #pragma unroll
  for (int off = 32; off > 0; off >>= 1) v += __shfl_down(v, off, 64);
  __shared__ float s[4];
  __syncthreads();
  if ((threadIdx.x & 63) == 0) s[threadIdx.x >> 6] = v;
  __syncthreads();
  return (s[0] + s[1]) + (s[2] + s[3]);
}

// one launch: blockIdx.y selects tensor {0:w_up,1:w_r1,2:w_r2}
__global__ void abssum3_kernel(const float* __restrict__ w0, const float* __restrict__ w1,
                               const float* __restrict__ w2, float* __restrict__ out) {
  int y = blockIdx.y;
  const float* w = (y == 0) ? w0 : (y == 1) ? w1 : w2;
  int n = (y == 0) ? NUP : NR;
  int idx = blockIdx.x * 256 + threadIdx.x;
  float s = 0.f;
  for (int i = idx; i < n; i += gridDim.x * 256) s += fabsf(w[i]);
  s = block_reduce_sum_256(s);
  if (threadIdx.x == 0) atomicAdd(out + y, s);
}

// ---------------- ternarize + repack, one launch; layout [tap][kq32][co512][16] ----------------
__global__ void tern_all_kernel(const float* __restrict__ wu, const float* __restrict__ w1,
                                const float* __restrict__ w2, int8_t* __restrict__ ou,
                                int8_t* __restrict__ o1, int8_t* __restrict__ o2,
                                const float* __restrict__ wsum) {
  int y = blockIdx.y;
  int idx = blockIdx.x * 256 + threadIdx.x;
  if (y == 0) {
    if (idx >= NUP) return;
    float mean = wsum[0] * (1.0f / (float)NUP);
    float scale = 1.0f / fmaxf(mean, 1e-5f);
    float t = rintf(wu[idx] * scale);
    t = fminf(fmaxf(t, -1.f), 1.f);
    int ci = idx >> 11;
    int co = (idx >> 2) & 511;
    int k = idx & 3;
    // ptap order: parity0 {k=3,k=1}, parity1 {k=2,k=0}
    int ptap = (k == 3) ? 0 : (k == 1) ? 1 : (k == 2) ? 2 : 3;
    ou[(((size_t)ptap * 32 + (ci >> 4)) * 512 + co) * 16 + (ci & 15)] = (int8_t)t;
  } else {
    if (idx >= NR) return;
    const float* w = (y == 1) ? w1 : w2;
    int8_t* o = (y == 1) ? o1 : o2;
    float mean = wsum[y] * (1.0f / (float)NR);
    float scale = 1.0f / fmaxf(mean, 1e-5f);
    float t = rintf(w[idx] * scale);
    t = fminf(fmaxf(t, -1.f), 1.f);
    int co = idx / 3584;
    int rem = idx - co * 3584;
    int ci = rem / 7;
    int k = rem - ci * 7;
    o[(((size_t)k * 32 + (ci >> 4)) * 512 + co) * 16 + (ci & 15)] = (int8_t)t;
  }
}

// ---------------- per-token activation quant; packed q layout [b][kq32][LinH][16] ----------------
__global__ void act_quant_kernel(const float* __restrict__ x, int8_t* __restrict__ qd,
                                 float* __restrict__ inv, int Lb, int lbsh, int LinH) {
  int tok = blockIdx.x;
  int b = tok >> lbsh;
  int t = tok & (Lb - 1);
  const float* row = x + (size_t)tok * C_;
  int tid = threadIdx.x;
  float v0 = row[tid];
  float v1 = row[tid + 256];
  float m = fmaxf(fabsf(v0), fabsf(v1));
  #pragma unroll
  for (int off = 32; off > 0; off >>= 1) m = fmaxf(m, __shfl_down(m, off, 64));
  __shared__ float s[4];
  __shared__ __align__(16) int8_t sq[512];
  if ((tid & 63) == 0) s[tid >> 6] = m;
  __syncthreads();
  m = fmaxf(fmaxf(s[0], s[1]), fmaxf(s[2], s[3]));
  float scale = 127.0f / fmaxf(m, 1e-5f);
  float q0 = fminf(fmaxf(rintf(v0 * scale), -128.f), 127.f);
  float q1 = fminf(fmaxf(rintf(v1 * scale), -128.f), 127.f);
  sq[tid] = (int8_t)q0;
  sq[tid + 256] = (int8_t)q1;
  __syncthreads();
  if (tid < 32)
    *(v4i*)(qd + ((size_t)(b * 32 + tid) * LinH + 8 + t) * 16) = *(const v4i*)(sq + tid * 16);
  if (tid == 0) inv[(size_t)b * LinH + 8 + t] = 1.0f / scale;
}

// ---------------- MFMA conv: barrier-free per-tap int8 GEMM, depth-4 pipeline ----------------
// Block 128 thr (2 waves), tile 32(M) x 128(N); wave w covers cols [64w, 64w+64).
// sA[kq32][row40][16] staged once (buf row r <-> token t0-4+r); ONE barrier; K-loop is
// pure dataflow with depth-4 rolling prefetch that crosses tap boundaries (the per-tap
// i32->fp32 fold overlaps the next tap's in-flight loads).
template<int NTAPS, bool CONVT>
__global__ __launch_bounds__(128, 2)
void conv_mfma(const int8_t* __restrict__ qin, const float* __restrict__ invp, int LinH,
               const int8_t* __restrict__ wq, const float* __restrict__ wsum, int widx,
               float wninv, const float* __restrict__ bias, const float* __restrict__ res,
               float* __restrict__ outp, int Lout, int do_silu) {
  __shared__ __align__(16) int8_t sA[32 * 40 * 16];  // 20480 B
  __shared__ float sInv[40];

  const int tid = threadIdx.x;
  const int w = tid >> 6, lane = tid & 63, q = lane >> 5, l31 = lane & 31;
  const int n0 = (blockIdx.x & 3) * 128;
  const int t0 = (blockIdx.x >> 2) * 32;
  const int b = blockIdx.y;
  int s0 = -3;
  const int8_t* wq_p = wq;
  float* out_b = outp + (size_t)b * Lout * 512;
  int rstride = 512;
  if (CONVT) {
    int parity = blockIdx.z;
    s0 = parity - 1;
    wq_p += (size_t)parity * 2 * 32 * 512 * 16;
    out_b += parity * 512;
    rstride = 1024;
  }
  const int8_t* qin_b = qin + (size_t)b * 32 * LinH * 16;
  const float* inv_b = invp + (size_t)b * LinH + 8;

  // stage A once: 1280 units of 16B, [kq32][row40][16]
  #pragma unroll
  for (int i = 0; i < 10; ++i) {
    int u = i * 128 + tid;
    int kq = u / 40;
    int row = u - kq * 40;
    gl16(qin_b + ((size_t)kq * LinH + (size_t)(t0 + 4 + row)) * 16,
         sA + (size_t)(i * 128 + w * 64) * 16);
  }
  if (tid < 40) sInv[tid] = inv_b[t0 - 4 + tid];
  __syncthreads();  // the ONLY barrier

  float fs0[16], fs1[16];
  #pragma unroll
  for (int r = 0; r < 16; ++r) { fs0[r] = 0.f; fs1[r] = 0.f; }

  const int nw = n0 + w * 64;

  // depth-4 pipeline registers
  v4i afp[4], b0p[4], b1p[4];
  // prologue: steps (tap 0, ks 0..3)
  #pragma unroll
  for (int i = 0; i < 4; ++i) {
    int kq32 = i * 2 + q;
    afp[i] = *(const v4i*)(sA + ((size_t)kq32 * 40 + 4 + s0 + l31) * 16);
    const int8_t* bp = wq_p + (((size_t)kq32 * 512) + nw + l31) * 16;
    b0p[i] = *(const v4i*)bp;
    b1p[i] = *(const v4i*)(bp + 512);
  }

  for (int tap = 0; tap < NTAPS; ++tap) {
    const int shift = s0 + tap;
    v16i acc0{}, acc1{};
    #pragma unroll
    for (int r = 0; r < 16; ++r) { acc0[r] = 0; acc1[r] = 0; }
    #pragma unroll
    for (int ks = 0; ks < 16; ++ks) {
      const int slot = ks & 3;
      v4i a_c = afp[slot], b0_c = b0p[slot], b1_c = b1p[slot];
      if (ks < 12) {               // prefetch same tap, step ks+4
        int kq32 = (ks + 4) * 2 + q;
        afp[slot] = *(const v4i*)(sA + ((size_t)kq32 * 40 + 4 + shift + l31) * 16);
        const int8_t* bp = wq_p + (((size_t)(tap * 32 + kq32) * 512) + nw + l31) * 16;
        b0p[slot] = *(const v4i*)bp;
        b1p[slot] = *(const v4i*)(bp + 512);
      } else if (tap + 1 < NTAPS) { // prefetch next tap, step ks-12
        int kq32 = (ks - 12) * 2 + q;
        afp[slot] = *(const v4i*)(sA + ((size_t)kq32 * 40 + 4 + shift + 1 + l31) * 16);
        const int8_t* bp = wq_p + (((size_t)((tap + 1) * 32 + kq32) * 512) + nw + l31) * 16;
        b0p[slot] = *(const v4i*)bp;
        b1p[slot] = *(const v4i*)(bp + 512);
      }
      acc0 = __builtin_amdgcn_mfma_i32_32x32x32_i8(a_c, b0_c, acc0, 0, 0, 0);
      acc1 = __builtin_amdgcn_mfma_i32_32x32x32_i8(a_c, b1_c, acc1, 0, 0, 0);
    }
    // fold i32 -> fp32 with per-input-row scale (overlaps next tap's in-flight loads)
    #pragma unroll
    for (int r = 0; r < 16; ++r) {
      int ro = (r & 3) + 8 * (r >> 2) + 4 * q;
      float sc = sInv[4 + shift + ro];
      fs0[r] = fmaf((float)acc0[r], sc, fs0[r]);
      fs1[r] = fmaf((float)acc1[r], sc, fs1[r]);
    }
  }

  float wdq = fmaxf(wsum[widx] * wninv, 1e-5f);
  #pragma unroll
  for (int nt = 0; nt < 2; ++nt) {
    int col = nw + nt * 32 + l31;
    float bv = bias[col];
    #pragma unroll
    for (int r = 0; r < 16; ++r) {
      int row = t0 + (r & 3) + 8 * (r >> 2) + 4 * q;
      float y = (nt == 0 ? fs0[r] : fs1[r]) * wdq + bv;
      if (do_silu) y = y / (1.0f + expf(-y));
      if (res) y += res[((size_t)b * Lout + row) * 512 + col];
      out_b[(size_t)row * rstride + col] = y;
    }
  }
}

// ---------------- LayerNorm over channels ----------------
__global__ void ln_kernel(const float* __restrict__ x, const float* __restrict__ g,
                          const float* __restrict__ be, float* __restrict__ out) {
  int tok = blockIdx.x;
  const float* row = x + (size_t)tok * C_;
  int tid = threadIdx.x;
  float v0 = row[tid];
  float v1 = row[tid + 256];
  float total = block_reduce_sum_256(v0 + v1);
  float mu = total * (1.0f / (float)C_);
  float d0 = v0 - mu, d1 = v1 - mu;
  float vs = block_reduce_sum_256(d0 * d0 + d1 * d1);
  float var = vs * (1.0f / (float)C_);
  float r = 1.0f / sqrtf(var + 1e-5f);
  size_t base = (size_t)tok * C_;
  out[base + tid] = d0 * r * g[tid] + be[tid];
  out[base + tid + 256] = d1 * r * g[tid + 256] + be[tid + 256];
}

// ---------------- launch ----------------

extern "C" void kernel_launch(void* const* d_in, const int* in_sizes, int n_in,
                              void* d_out, int out_size, void* d_ws, size_t ws_size,
                              hipStream_t stream) {
  const float* x    = (const float*)d_in[0];
  const float* w_up = (const float*)d_in[1];
  const float* b_up = (const float*)d_in[2];
  const float* w_r1 = (const float*)d_in[3];
  const float* b_r1 = (const float*)d_in[4];
  const float* w_r2 = (const float*)d_in[5];
  const float* b_r2 = (const float*)d_in[6];
  const float* ln_w = (const float*)d_in[7];
  const float* ln_b = (const float*)d_in[8];
  float* out = (float*)d_out;

  const int LXH = T_ + 16;   // 2064 rows per batch (halo 8 each side)
  const int LHH = L_ + 16;   // 4112

  char* ws = (char*)d_ws;
  size_t off = 0;
  auto alloc = [&](size_t sz) { size_t p = off; off += (sz + 255) & ~(size_t)255; return p; };
  // wsum, qx, qh contiguous -> one zeroing memset
  float*  wsum = (float*) (ws + alloc(256));
  int8_t* qx   = (int8_t*)(ws + alloc((size_t)B_ * 32 * LXH * 16));   // 2.1 MB
  int8_t* qh   = (int8_t*)(ws + alloc((size_t)B_ * 32 * LHH * 16));   // 4.2 MB
  size_t zero_bytes = off;
  float*  invx = (float*) (ws + alloc((size_t)B_ * LXH * 4));
  float*  invh = (float*) (ws + alloc((size_t)B_ * LHH * 4));
  int8_t* wqup = (int8_t*)(ws + alloc((size_t)4 * 32 * 512 * 16));    // 1 MB
  int8_t* wq1  = (int8_t*)(ws + alloc((size_t)7 * 32 * 512 * 16));    // 1.8 MB
  int8_t* wq2  = (int8_t*)(ws + alloc((size_t)7 * 32 * 512 * 16));    // 1.8 MB
  float*  h    = (float*) (ws + alloc((size_t)B_ * L_ * C_ * 4));     // 16.8 MB
  float*  r    = (float*) (ws + alloc((size_t)B_ * L_ * C_ * 4));     // 16.8 MB

  hipMemsetAsync(ws, 0, zero_bytes, stream);  // wsum + qx + qh (zero halos)

  abssum3_kernel<<<dim3(256, 3), 256, 0, stream>>>(w_up, w_r1, w_r2, wsum);
  tern_all_kernel<<<dim3(NR / 256, 3), 256, 0, stream>>>(w_up, w_r1, w_r2,
                                                         wqup, wq1, wq2, wsum);

  act_quant_kernel<<<B_ * T_, 256, 0, stream>>>(x, qx, invx, T_, 11, LXH);

  // convT: grid (4 ntiles * 64 mtiles, B, parity); block tile 32M x 128N
  conv_mfma<2, true><<<dim3(4 * 64, B_, 2), 128, 0, stream>>>(
      qx, invx, LXH, wqup, wsum, 0, 1.0f / (float)NUP, b_up, nullptr, h, L_, 0);

  act_quant_kernel<<<B_ * L_, 256, 0, stream>>>(h, qh, invh, L_, 12, LHH);

  conv_mfma<7, false><<<dim3(4 * 128, B_, 1), 128, 0, stream>>>(
      qh, invh, LHH, wq1, wsum, 1, 1.0f / (float)NR, b_r1, nullptr, r, L_, 1);

  act_quant_kernel<<<B_ * L_, 256, 0, stream>>>(r, qh, invh, L_, 12, LHH);

  conv_mfma<7, false><<<dim3(4 * 128, B_, 1), 128, 0, stream>>>(
      qh, invh, LHH, wq2, wsum, 2, 1.0f / (float)NR, b_r2, h, r, L_, 0);

  ln_kernel<<<B_ * L_, 256, 0, stream>>>(r, ln_w, ln_b, out);
}